// Round 3
// baseline (515.968 us; speedup 1.0000x reference)
//
#include <hip/hip_runtime.h>
#include <stdint.h>

#define DEV __device__ __forceinline__

typedef __attribute__((ext_vector_type(8))) short short8;
typedef __attribute__((ext_vector_type(4))) float floatx4;

// problem dims
#define BATCH 128
#define TT    197
#define DD    768
#define NH    12
#define NROWS (BATCH*TT)   // 25216 = 197*128
#define G4H   3072         // 4*H rows of gate weights
#define MT    197          // m-tiles (128 rows each)
#define NT    6            // n-tiles (128 cols each)

DEV uint16_t f2bf(float f) {
    union { float f; uint32_t u; } v; v.f = f;
    uint32_t r = (v.u + 0x7FFF + ((v.u >> 16) & 1)) >> 16;  // RNE
    return (uint16_t)r;
}

DEV floatx4 mfma16(short8 a, short8 b, floatx4 c) {
    return __builtin_amdgcn_mfma_f32_16x16x32_bf16(a, b, c, 0, 0, 0);
}

DEV float sigf(float x)   { return __builtin_amdgcn_rcpf(1.0f + __expf(-x)); }
DEV float tanhf_(float x) { return 1.0f - 2.0f * __builtin_amdgcn_rcpf(1.0f + __expf(2.0f * x)); }

// async global->LDS, 16B per lane; lds base must be wave-uniform (HW adds lane*16)
DEV void async16(const uint16_t* g, uint16_t* l) {
    __builtin_amdgcn_global_load_lds(
        (const __attribute__((address_space(1))) unsigned int*)g,
        (__attribute__((address_space(3))) unsigned int*)l,
        16, 0, 0);
}

// ---------------- fused fp32 -> bf16 conversion (all tensors, one launch) ----
struct CvtArgs {
    const float* src[7];
    uint16_t*    dst[7];
    int          n4[7];    // element count / 4
    int          nseg;
};

__global__ void cvt_multi(CvtArgs a) {
    int tid = blockIdx.x * blockDim.x + threadIdx.x;
    int stride = gridDim.x * blockDim.x;
    for (int s = 0; s < a.nseg; s++) {
        const float4* src = (const float4*)a.src[s];
        ushort4* dst = (ushort4*)a.dst[s];
        int n4 = a.n4[s];
        for (int i = tid; i < n4; i += stride) {
            float4 v = src[i];
            ushort4 o;
            o.x = f2bf(v.x); o.y = f2bf(v.y); o.z = f2bf(v.z); o.w = f2bf(v.w);
            dst[i] = o;
        }
    }
}

// ---------------- bf16 MFMA GEMM: C[M,N] = A[M,K] @ Bw[N,K]^T + bias ----------
// 128x128 tile, 4 waves each owning a 64x64 quadrant. BK=64 (2 K-steps per
// barrier pair). LDS identity-chunk layout (staging addr == frag-read addr).
// 1-D grid with XCD swizzle: bid%8 = XCD; each XCD gets m-rows {c, c+8, ...}
// with the NT same-m blocks on consecutive slots so the A-slab is fetched into
// that XCD's L2 once and hit by the other 5 blocks.
// LAYOUT: 0 = plain [M][Ntot]; 1 = LSTM pre layout [t][head][batch][64].
template<int STORE_BF16, int LAYOUT>
__global__ __launch_bounds__(256) void gemm128(
    const uint16_t* __restrict__ A,    // [M][K] bf16
    const uint16_t* __restrict__ Bw,   // [N][K] bf16 (weight; transposed use)
    const float*    __restrict__ bias, // [N] fp32
    void*           __restrict__ C,
    int K, int Ntot)
{
    __shared__ __attribute__((aligned(16))) uint16_t As[2][8 * 512];  // 16 KB
    __shared__ __attribute__((aligned(16))) uint16_t Bs[2][8 * 512];  // 16 KB

    // XCD swizzle
    const int bid = blockIdx.x;
    const int c   = bid & 7;
    const int j   = bid >> 3;
    const int mt_ = c + 8 * (j / NT);
    const int nt_ = j % NT;
    if (mt_ >= MT) return;
    const int m0 = mt_ * 128;
    const int n0 = nt_ * 128;

    const int tid  = threadIdx.x;
    const int wv   = tid >> 6;
    const int lane = tid & 63;
    const int ln   = lane & 15;
    const int q    = lane >> 4;
    const int wm   = wv >> 1;   // wave quadrant row
    const int wn   = wv & 1;    // wave quadrant col

    floatx4 acc[4][4];
#pragma unroll
    for (int a = 0; a < 4; a++)
#pragma unroll
        for (int b = 0; b < 4; b++) acc[a][b] = (floatx4){0.f, 0.f, 0.f, 0.f};

    // wave wv stages A chunks {2wv,2wv+1} and B chunks {2wv,2wv+1}, both k-halves
    const uint16_t* gA0 = A  + (size_t)(m0 + (2*wv+0)*16 + ln) * K + q*8;
    const uint16_t* gA1 = A  + (size_t)(m0 + (2*wv+1)*16 + ln) * K + q*8;
    const uint16_t* gB0 = Bw + (size_t)(n0 + (2*wv+0)*16 + ln) * K + q*8;
    const uint16_t* gB1 = Bw + (size_t)(n0 + (2*wv+1)*16 + ln) * K + q*8;
    uint16_t* lA0h0 = &As[0][(2*wv+0)*512]; uint16_t* lA0h1 = &As[1][(2*wv+0)*512];
    uint16_t* lA1h0 = &As[0][(2*wv+1)*512]; uint16_t* lA1h1 = &As[1][(2*wv+1)*512];
    uint16_t* lB0h0 = &Bs[0][(2*wv+0)*512]; uint16_t* lB0h1 = &Bs[1][(2*wv+0)*512];
    uint16_t* lB1h0 = &Bs[0][(2*wv+1)*512]; uint16_t* lB1h1 = &Bs[1][(2*wv+1)*512];

    for (int k0 = 0; k0 < K; k0 += 64) {
        __syncthreads();                 // previous iteration's frag reads done
        async16(gA0 + k0,      lA0h0);
        async16(gA0 + k0 + 32, lA0h1);
        async16(gA1 + k0,      lA1h0);
        async16(gA1 + k0 + 32, lA1h1);
        async16(gB0 + k0,      lB0h0);
        async16(gB0 + k0 + 32, lB0h1);
        async16(gB1 + k0,      lB1h0);
        async16(gB1 + k0 + 32, lB1h1);
        __syncthreads();                 // barrier drains vmcnt -> tiles ready

#pragma unroll
        for (int h = 0; h < 2; h++) {
            short8 af[4], bf[4];
#pragma unroll
            for (int mt = 0; mt < 4; mt++)
                af[mt] = *(const short8*)&As[h][(wm*4 + mt)*512 + lane*8];
#pragma unroll
            for (int nt = 0; nt < 4; nt++)
                bf[nt] = *(const short8*)&Bs[h][(wn*4 + nt)*512 + lane*8];
#pragma unroll
            for (int mt = 0; mt < 4; mt++)
#pragma unroll
                for (int nt = 0; nt < 4; nt++)
                    acc[mt][nt] = mfma16(af[mt], bf[nt], acc[mt][nt]);
        }
    }

    // epilogue: C/D layout col(n)=lane&15, row(m)=(lane>>4)*4+r
#pragma unroll
    for (int mt = 0; mt < 4; mt++)
#pragma unroll
        for (int nt = 0; nt < 4; nt++) {
            int n = n0 + (wn*4 + nt)*16 + ln;
            float bv = bias[n];
#pragma unroll
            for (int r = 0; r < 4; r++) {
                int m = m0 + (wm*4 + mt)*16 + q*4 + r;   // = b*197 + t
                float val = acc[mt][nt][r] + bv;
                if (LAYOUT == 1) {
                    int b = m / 197; int t = m - b*197;
                    int head = n >> 6; int d = n & 63;
                    size_t off = ((size_t)(t*NH + head)*BATCH + b)*64 + d;
                    ((uint16_t*)C)[off] = f2bf(val);
                } else {
                    size_t off = (size_t)m * Ntot + n;
                    if (STORE_BF16) ((uint16_t*)C)[off] = f2bf(val);
                    else            ((float*)C)[off]    = val;
                }
            }
        }
}

// ---------------- fused bidirectional multi-head LSTM ----------------
// grid (8 batch-chunks, 12 heads, 2 dirs), 256 threads = 4 waves.
// wave w owns units [16w,16w+16): 4 gate-type C-tiles [16 units x 16 batches].
// Persistent weight A-frags in registers; fp32 c-state in registers.
// h exchanged via DOUBLE-BUFFERED padded LDS -> ONE barrier per step.
// x loads fully coalesced via the [t][head][b][64] pre layout (2 KB/wave/step).
__global__ __launch_bounds__(256) void lstm_fused(
    const uint16_t* __restrict__ pre,   // [T][head][B][64] bf16
    const uint16_t* __restrict__ wih_f, const uint16_t* __restrict__ whh_f,
    const uint16_t* __restrict__ wih_r, const uint16_t* __restrict__ whh_r,
    const float* __restrict__ bih_f, const float* __restrict__ bhh_f,
    const float* __restrict__ bih_r, const float* __restrict__ bhh_r,
    uint16_t* __restrict__ hout)        // [B][T][1536] bf16
{
    __shared__ __attribute__((aligned(16))) uint16_t hbuf[2][16][72];

    const int tid  = threadIdx.x;
    const int wv   = tid >> 6;
    const int lane = tid & 63;
    const int ln   = lane & 15;
    const int q    = lane >> 4;
    const int b0   = blockIdx.x * 16;
    const int head = blockIdx.y;
    const int dir  = blockIdx.z;
    const int ub   = wv * 16;

    const uint16_t* wih = dir ? wih_r : wih_f;
    const uint16_t* whh = dir ? whh_r : whh_f;
    const float*    bih = dir ? bih_r : bih_f;
    const float*    bhh = dir ? bhh_r : bhh_f;

    // persistent A-fragments: [gate type][k-step]
    short8 aih[4][2], ahh[4][2];
#pragma unroll
    for (int t = 0; t < 4; t++) {
        size_t row = (size_t)(t*768 + head*64 + ub + ln);
#pragma unroll
        for (int s = 0; s < 2; s++) {
            aih[t][s] = *(const short8*)(wih + row*768 + head*64 + s*32 + q*8);
            ahh[t][s] = *(const short8*)(whh + row*768 + head*64 + s*32 + q*8);
        }
    }
    float biasv[4][4];
#pragma unroll
    for (int t = 0; t < 4; t++)
#pragma unroll
        for (int r = 0; r < 4; r++) {
            int row = t*768 + head*64 + ub + q*4 + r;
            biasv[t][r] = bih[row] + bhh[row];
        }

    for (int i = tid; i < 2*16*72; i += 256) ((uint16_t*)hbuf)[i] = 0;
    float c[4] = {0.f, 0.f, 0.f, 0.f};
    __syncthreads();

    // x: [t][head][b][64]; wave reads 2 KB contiguous per step
    const uint16_t* xbase = pre + (size_t)head*BATCH*64 + (size_t)(b0 + ln)*64 + q*8;
    int t_cur = dir ? (TT - 1) : 0;
    const int tstep = dir ? -1 : 1;
    size_t xo = (size_t)t_cur * NH * BATCH * 64;
    short8 xv0 = *(const short8*)(xbase + xo);
    short8 xv1 = *(const short8*)(xbase + xo + 32);

    for (int step = 0; step < TT; step++) {
        short8 cx0 = xv0, cx1 = xv1;
        int t_next = t_cur + tstep;
        if (step + 1 < TT) {   // prefetch next timestep's x (coalesced)
            size_t xo2 = (size_t)t_next * NH * BATCH * 64;
            xv0 = *(const short8*)(xbase + xo2);
            xv1 = *(const short8*)(xbase + xo2 + 32);
        }
        const int pb = (step + 1) & 1;   // buffer holding h_{step-1}
        const int cb = step & 1;         // buffer to write h_step
        short8 hb0 = *(const short8*)&hbuf[pb][ln][0*32 + q*8];
        short8 hb1 = *(const short8*)&hbuf[pb][ln][1*32 + q*8];

        floatx4 acc[4];
#pragma unroll
        for (int t = 0; t < 4; t++)
            acc[t] = (floatx4){biasv[t][0], biasv[t][1], biasv[t][2], biasv[t][3]};
#pragma unroll
        for (int t = 0; t < 4; t++) {
            acc[t] = mfma16(aih[t][0], cx0, acc[t]);
            acc[t] = mfma16(ahh[t][0], hb0, acc[t]);
            acc[t] = mfma16(aih[t][1], cx1, acc[t]);
            acc[t] = mfma16(ahh[t][1], hb1, acc[t]);
        }

        union { uint16_t s[4]; uint2 v; } hp;
#pragma unroll
        for (int r = 0; r < 4; r++) {
            float ig = sigf(acc[0][r]);
            float fg = sigf(acc[1][r]);
            float gg = tanhf_(acc[2][r]);
            float og = sigf(acc[3][r]);
            c[r] = fg * c[r] + ig * gg;
            float hv = og * tanhf_(c[r]);
            hp.s[r] = f2bf(hv);
        }

        // write h_step into the OTHER buffer: no conflict with laggard readers
        *(uint2*)&hbuf[cb][ln][ub + q*4] = hp.v;
        __syncthreads();   // single barrier: h_step visible, h_{step-1} reads done

        {   // coalesced h -> global (read back from LDS)
            int bl = tid >> 4;
            int dw = tid & 15;
            uint2 v = *(const uint2*)&hbuf[cb][bl][dw*4];
            size_t off = ((size_t)(b0 + bl)*TT + t_cur) * 1536 + dir*768 + head*64 + dw*4;
            *(uint2*)(hout + off) = v;
        }
        t_cur = t_next;
    }
}

extern "C" void kernel_launch(void* const* d_in, const int* in_sizes, int n_in,
                              void* d_out, int out_size, void* d_ws, size_t ws_size,
                              hipStream_t stream) {
    (void)in_sizes; (void)n_in; (void)out_size; (void)ws_size;
    const float* x     = (const float*)d_in[0];
    const float* pre_w = (const float*)d_in[1];
    const float* pre_b = (const float*)d_in[2];
    const float* wihf  = (const float*)d_in[3];
    const float* whhf  = (const float*)d_in[4];
    const float* bihf  = (const float*)d_in[5];
    const float* bhhf  = (const float*)d_in[6];
    const float* wihr  = (const float*)d_in[7];
    const float* whhr  = (const float*)d_in[8];
    const float* bihr  = (const float*)d_in[9];
    const float* bhhr  = (const float*)d_in[10];
    const float* projw = (const float*)d_in[11];
    const float* projb = (const float*)d_in[12];
    float* out = (float*)d_out;

    // workspace layout (bf16 elements), ~177 MB total
    uint16_t* W = (uint16_t*)d_ws;
    uint16_t* xb     = W; W += (size_t)NROWS * DD;     // x bf16       [B*T][768]
    uint16_t* bwpre  = W; W += (size_t)DD * DD;
    uint16_t* bwihf  = W; W += (size_t)G4H * DD;
    uint16_t* bwhhf  = W; W += (size_t)G4H * DD;
    uint16_t* bwihr  = W; W += (size_t)G4H * DD;
    uint16_t* bwhhr  = W; W += (size_t)G4H * DD;
    uint16_t* bwproj = W; W += (size_t)DD * 2 * DD;
    uint16_t* preb   = W; W += (size_t)NROWS * DD;     // [T][head][B][64] bf16
    uint16_t* houtb  = W; W += (size_t)NROWS * 2 * DD; // [B][T][1536] bf16

    CvtArgs ca;
    ca.src[0] = x;     ca.dst[0] = xb;     ca.n4[0] = (int)((size_t)NROWS * DD / 4);
    ca.src[1] = pre_w; ca.dst[1] = bwpre;  ca.n4[1] = DD * DD / 4;
    ca.src[2] = wihf;  ca.dst[2] = bwihf;  ca.n4[2] = G4H * DD / 4;
    ca.src[3] = whhf;  ca.dst[3] = bwhhf;  ca.n4[3] = G4H * DD / 4;
    ca.src[4] = wihr;  ca.dst[4] = bwihr;  ca.n4[4] = G4H * DD / 4;
    ca.src[5] = whhr;  ca.dst[5] = bwhhr;  ca.n4[5] = G4H * DD / 4;
    ca.src[6] = projw; ca.dst[6] = bwproj; ca.n4[6] = DD * 2 * DD / 4;
    ca.nseg = 7;
    hipLaunchKernelGGL(cvt_multi, dim3(1024), dim3(256), 0, stream, ca);

    const int RPX = (MT + 7) / 8;            // m-rows per XCD = 25
    const int GBLK = 8 * RPX * NT;           // 1200 blocks (some no-op)

    // S1: pre = x @ pre_w.T + pre_b, bf16, stored [t][head][b][64]
    hipLaunchKernelGGL((gemm128<1, 1>), dim3(GBLK), dim3(256), 0, stream,
                       xb, bwpre, pre_b, (void*)preb, DD, DD);
    // S2+S3: bidirectional block-diagonal LSTM
    hipLaunchKernelGGL(lstm_fused, dim3(8, 12, 2), dim3(256), 0, stream,
                       preb, bwihf, bwhhf, bwihr, bwhhr,
                       bihf, bhhf, bihr, bhhr, houtb);
    // S4: out = [hf|hr] @ proj_w.T + proj_b, fp32
    hipLaunchKernelGGL((gemm128<0, 0>), dim3(GBLK), dim3(256), 0, stream,
                       houtb, bwproj, projb, (void*)out, 2 * DD, DD);
}

// Round 4
// 495.673 us; speedup vs baseline: 1.0409x; 1.0409x over previous
//
#include <hip/hip_runtime.h>
#include <stdint.h>

#define DEV __device__ __forceinline__

typedef __attribute__((ext_vector_type(8))) short short8;
typedef __attribute__((ext_vector_type(4))) float floatx4;

// problem dims
#define BATCH 128
#define TT    197
#define DD    768
#define NH    12
#define NROWS (BATCH*TT)   // 25216 = 197*128
#define G4H   3072         // 4*H rows of gate weights
#define MT    197          // m-tiles (128 rows each)
#define NT    6            // n-tiles (128 cols each)

DEV uint16_t f2bf(float f) {
    union { float f; uint32_t u; } v; v.f = f;
    uint32_t r = (v.u + 0x7FFF + ((v.u >> 16) & 1)) >> 16;  // RNE
    return (uint16_t)r;
}

DEV floatx4 mfma16(short8 a, short8 b, floatx4 c) {
    return __builtin_amdgcn_mfma_f32_16x16x32_bf16(a, b, c, 0, 0, 0);
}

DEV float sigf(float x)   { return __builtin_amdgcn_rcpf(1.0f + __expf(-x)); }
DEV float tanhf_(float x) { return 1.0f - 2.0f * __builtin_amdgcn_rcpf(1.0f + __expf(2.0f * x)); }

// async global->LDS, 16B per lane; lds base must be wave-uniform (HW adds lane*16)
DEV void async16(const uint16_t* g, uint16_t* l) {
    __builtin_amdgcn_global_load_lds(
        (const __attribute__((address_space(1))) unsigned int*)g,
        (__attribute__((address_space(3))) unsigned int*)l,
        16, 0, 0);
}

#define CFENCE() asm volatile("" ::: "memory")

// ---------------- fused fp32 -> bf16 conversion (all tensors, one launch) ----
struct CvtArgs {
    const float* src[7];
    uint16_t*    dst[7];
    int          n4[7];    // element count / 4
    int          nseg;
};

__global__ void cvt_multi(CvtArgs a) {
    int tid = blockIdx.x * blockDim.x + threadIdx.x;
    int stride = gridDim.x * blockDim.x;
    for (int s = 0; s < a.nseg; s++) {
        const float4* src = (const float4*)a.src[s];
        ushort4* dst = (ushort4*)a.dst[s];
        int n4 = a.n4[s];
        for (int i = tid; i < n4; i += stride) {
            float4 v = src[i];
            ushort4 o;
            o.x = f2bf(v.x); o.y = f2bf(v.y); o.z = f2bf(v.z); o.w = f2bf(v.w);
            dst[i] = o;
        }
    }
}

// ---------------- pipelined bf16 MFMA GEMM: C[M,N] = A[M,K] @ Bw[N,K]^T + bias ----
// 128x128 tile, 4 waves each owning a 64x64 quadrant. BK=32.
// AITER-style software pipeline: 3 LDS buffers, prefetch depth 2, raw s_barrier +
// s_waitcnt vmcnt(8) so the next two iterations' global_load_lds stay IN FLIGHT
// across the barrier (vs __syncthreads' forced vmcnt(0) drain each iter).
// Tail iters issue clamped loads into a dump chunk so vmcnt arithmetic is constant.
// XCD swizzle: bid%8 = XCD; NT same-m blocks consecutive per XCD for L2 A-reuse.
// LAYOUT: 0 = plain [M][Ntot]; 1 = LSTM pre layout [t][head][batch][64].
template<int STORE_BF16, int LAYOUT>
__global__ __launch_bounds__(256) void gemm128p(
    const uint16_t* __restrict__ A,    // [M][K] bf16
    const uint16_t* __restrict__ Bw,   // [N][K] bf16 (weight; transposed use)
    const float*    __restrict__ bias, // [N] fp32
    void*           __restrict__ C,
    int K, int Ntot)
{
    __shared__ __attribute__((aligned(16))) uint16_t As[3][4096];  // 3 x 8 KB
    __shared__ __attribute__((aligned(16))) uint16_t Bs[3][4096];  // 3 x 8 KB
    __shared__ __attribute__((aligned(16))) uint16_t Dump[512];    // 1 KB trash

    // XCD swizzle
    const int bid = blockIdx.x;
    const int c   = bid & 7;
    const int j   = bid >> 3;
    const int mt_ = c + 8 * (j / NT);
    const int nt_ = j % NT;
    if (mt_ >= MT) return;
    const int m0 = mt_ * 128;
    const int n0 = nt_ * 128;

    const int tid  = threadIdx.x;
    const int wv   = tid >> 6;
    const int lane = tid & 63;
    const int ln   = lane & 15;
    const int q    = lane >> 4;
    const int wm   = wv >> 1;   // wave quadrant row
    const int wn   = wv & 1;    // wave quadrant col

    floatx4 acc[4][4];
#pragma unroll
    for (int a = 0; a < 4; a++)
#pragma unroll
        for (int b = 0; b < 4; b++) acc[a][b] = (floatx4){0.f, 0.f, 0.f, 0.f};

    // wave wv stages A chunks {2wv,2wv+1} and B chunks {2wv,2wv+1}
    const uint16_t* gA0 = A  + (size_t)(m0 + (2*wv+0)*16 + ln) * K + q*8;
    const uint16_t* gA1 = A  + (size_t)(m0 + (2*wv+1)*16 + ln) * K + q*8;
    const uint16_t* gB0 = Bw + (size_t)(n0 + (2*wv+0)*16 + ln) * K + q*8;
    const uint16_t* gB1 = Bw + (size_t)(n0 + (2*wv+1)*16 + ln) * K + q*8;

    const int NI = K >> 5;   // 24 (S1) or 48 (S4) — both divisible by 3

    auto stage = [&](int kiter, int buf) {
        int k0 = kiter * 32;
        const bool ok = k0 < K;          // wave-uniform
        if (!ok) k0 = 0;
        uint16_t* a0 = ok ? &As[buf][(2*wv+0)*512] : Dump;
        uint16_t* a1 = ok ? &As[buf][(2*wv+1)*512] : Dump;
        uint16_t* b0 = ok ? &Bs[buf][(2*wv+0)*512] : Dump;
        uint16_t* b1 = ok ? &Bs[buf][(2*wv+1)*512] : Dump;
        async16(gA0 + k0, a0);
        async16(gA1 + k0, a1);
        async16(gB0 + k0, b0);
        async16(gB1 + k0, b1);
    };

    stage(0, 0); stage(1, 1); stage(2, 2);

    for (int i = 0; i < NI; i += 3) {
#pragma unroll
        for (int u = 0; u < 3; u++) {
            CFENCE();
            __builtin_amdgcn_s_waitcnt(0x0F78);   // vmcnt(8): iter i+u's 4 loads landed
            __builtin_amdgcn_s_barrier();          // publish buf u (no vmcnt(0) drain!)
            CFENCE();

            short8 af[4], bf[4];
#pragma unroll
            for (int mt = 0; mt < 4; mt++)
                af[mt] = *(const short8*)&As[u][(wm*4 + mt)*512 + lane*8];
#pragma unroll
            for (int nt = 0; nt < 4; nt++)
                bf[nt] = *(const short8*)&Bs[u][(wn*4 + nt)*512 + lane*8];
#pragma unroll
            for (int mt = 0; mt < 4; mt++)
#pragma unroll
                for (int nt = 0; nt < 4; nt++)
                    acc[mt][nt] = mfma16(af[mt], bf[nt], acc[mt][nt]);

            CFENCE();
            __builtin_amdgcn_s_barrier();          // all waves done reading buf u
            CFENCE();
            stage(i + u + 3, u);                   // refill (dump-clamped past NI)
        }
    }
    __builtin_amdgcn_s_waitcnt(0x0F70);  // vmcnt(0): drain dump loads before endpgm

    // epilogue: C/D layout col(n)=lane&15, row(m)=(lane>>4)*4+r
#pragma unroll
    for (int mt = 0; mt < 4; mt++)
#pragma unroll
        for (int nt = 0; nt < 4; nt++) {
            int n = n0 + (wn*4 + nt)*16 + ln;
            float bv = bias[n];
#pragma unroll
            for (int r = 0; r < 4; r++) {
                int m = m0 + (wm*4 + mt)*16 + q*4 + r;   // = b*197 + t
                float val = acc[mt][nt][r] + bv;
                if (LAYOUT == 1) {
                    int b = m / 197; int t = m - b*197;
                    int head = n >> 6; int d = n & 63;
                    size_t off = ((size_t)(t*NH + head)*BATCH + b)*64 + d;
                    ((uint16_t*)C)[off] = f2bf(val);
                } else {
                    size_t off = (size_t)m * Ntot + n;
                    if (STORE_BF16) ((uint16_t*)C)[off] = f2bf(val);
                    else            ((float*)C)[off]    = val;
                }
            }
        }
}

// ---------------- fused bidirectional multi-head LSTM ----------------
// grid (8 batch-chunks, 12 heads, 2 dirs), 256 threads = 4 waves.
// wave w owns units [16w,16w+16): 4 gate-type C-tiles [16 units x 16 batches].
// Persistent weight A-frags in registers; fp32 c-state in registers.
// h exchanged via DOUBLE-BUFFERED padded LDS -> ONE barrier per step.
// x loads fully coalesced via the [t][head][b][64] pre layout (2 KB/wave/step).
__global__ __launch_bounds__(256) void lstm_fused(
    const uint16_t* __restrict__ pre,   // [T][head][B][64] bf16
    const uint16_t* __restrict__ wih_f, const uint16_t* __restrict__ whh_f,
    const uint16_t* __restrict__ wih_r, const uint16_t* __restrict__ whh_r,
    const float* __restrict__ bih_f, const float* __restrict__ bhh_f,
    const float* __restrict__ bih_r, const float* __restrict__ bhh_r,
    uint16_t* __restrict__ hout)        // [B][T][1536] bf16
{
    __shared__ __attribute__((aligned(16))) uint16_t hbuf[2][16][72];

    const int tid  = threadIdx.x;
    const int wv   = tid >> 6;
    const int lane = tid & 63;
    const int ln   = lane & 15;
    const int q    = lane >> 4;
    const int b0   = blockIdx.x * 16;
    const int head = blockIdx.y;
    const int dir  = blockIdx.z;
    const int ub   = wv * 16;

    const uint16_t* wih = dir ? wih_r : wih_f;
    const uint16_t* whh = dir ? whh_r : whh_f;
    const float*    bih = dir ? bih_r : bih_f;
    const float*    bhh = dir ? bhh_r : bhh_f;

    // persistent A-fragments: [gate type][k-step]
    short8 aih[4][2], ahh[4][2];
#pragma unroll
    for (int t = 0; t < 4; t++) {
        size_t row = (size_t)(t*768 + head*64 + ub + ln);
#pragma unroll
        for (int s = 0; s < 2; s++) {
            aih[t][s] = *(const short8*)(wih + row*768 + head*64 + s*32 + q*8);
            ahh[t][s] = *(const short8*)(whh + row*768 + head*64 + s*32 + q*8);
        }
    }
    float biasv[4][4];
#pragma unroll
    for (int t = 0; t < 4; t++)
#pragma unroll
        for (int r = 0; r < 4; r++) {
            int row = t*768 + head*64 + ub + q*4 + r;
            biasv[t][r] = bih[row] + bhh[row];
        }

    for (int i = tid; i < 2*16*72; i += 256) ((uint16_t*)hbuf)[i] = 0;
    float c[4] = {0.f, 0.f, 0.f, 0.f};
    __syncthreads();

    // x: [t][head][b][64]; wave reads 2 KB contiguous per step
    const uint16_t* xbase = pre + (size_t)head*BATCH*64 + (size_t)(b0 + ln)*64 + q*8;
    int t_cur = dir ? (TT - 1) : 0;
    const int tstep = dir ? -1 : 1;
    size_t xo = (size_t)t_cur * NH * BATCH * 64;
    short8 xv0 = *(const short8*)(xbase + xo);
    short8 xv1 = *(const short8*)(xbase + xo + 32);

    for (int step = 0; step < TT; step++) {
        short8 cx0 = xv0, cx1 = xv1;
        int t_next = t_cur + tstep;
        if (step + 1 < TT) {   // prefetch next timestep's x (coalesced)
            size_t xo2 = (size_t)t_next * NH * BATCH * 64;
            xv0 = *(const short8*)(xbase + xo2);
            xv1 = *(const short8*)(xbase + xo2 + 32);
        }
        const int pb = (step + 1) & 1;   // buffer holding h_{step-1}
        const int cb = step & 1;         // buffer to write h_step
        short8 hb0 = *(const short8*)&hbuf[pb][ln][0*32 + q*8];
        short8 hb1 = *(const short8*)&hbuf[pb][ln][1*32 + q*8];

        floatx4 acc[4];
#pragma unroll
        for (int t = 0; t < 4; t++)
            acc[t] = (floatx4){biasv[t][0], biasv[t][1], biasv[t][2], biasv[t][3]};
#pragma unroll
        for (int t = 0; t < 4; t++) {
            acc[t] = mfma16(aih[t][0], cx0, acc[t]);
            acc[t] = mfma16(ahh[t][0], hb0, acc[t]);
            acc[t] = mfma16(aih[t][1], cx1, acc[t]);
            acc[t] = mfma16(ahh[t][1], hb1, acc[t]);
        }

        union { uint16_t s[4]; uint2 v; } hp;
#pragma unroll
        for (int r = 0; r < 4; r++) {
            float ig = sigf(acc[0][r]);
            float fg = sigf(acc[1][r]);
            float gg = tanhf_(acc[2][r]);
            float og = sigf(acc[3][r]);
            c[r] = fg * c[r] + ig * gg;
            float hv = og * tanhf_(c[r]);
            hp.s[r] = f2bf(hv);
        }

        // write h_step into the OTHER buffer: no conflict with laggard readers
        *(uint2*)&hbuf[cb][ln][ub + q*4] = hp.v;
        __syncthreads();   // single barrier: h_step visible, h_{step-1} reads done

        {   // coalesced h -> global (read back from LDS)
            int bl = tid >> 4;
            int dw = tid & 15;
            uint2 v = *(const uint2*)&hbuf[cb][bl][dw*4];
            size_t off = ((size_t)(b0 + bl)*TT + t_cur) * 1536 + dir*768 + head*64 + dw*4;
            *(uint2*)(hout + off) = v;
        }
        t_cur = t_next;
    }
}

extern "C" void kernel_launch(void* const* d_in, const int* in_sizes, int n_in,
                              void* d_out, int out_size, void* d_ws, size_t ws_size,
                              hipStream_t stream) {
    (void)in_sizes; (void)n_in; (void)out_size; (void)ws_size;
    const float* x     = (const float*)d_in[0];
    const float* pre_w = (const float*)d_in[1];
    const float* pre_b = (const float*)d_in[2];
    const float* wihf  = (const float*)d_in[3];
    const float* whhf  = (const float*)d_in[4];
    const float* bihf  = (const float*)d_in[5];
    const float* bhhf  = (const float*)d_in[6];
    const float* wihr  = (const float*)d_in[7];
    const float* whhr  = (const float*)d_in[8];
    const float* bihr  = (const float*)d_in[9];
    const float* bhhr  = (const float*)d_in[10];
    const float* projw = (const float*)d_in[11];
    const float* projb = (const float*)d_in[12];
    float* out = (float*)d_out;

    // workspace layout (bf16 elements), ~177 MB total
    uint16_t* W = (uint16_t*)d_ws;
    uint16_t* xb     = W; W += (size_t)NROWS * DD;     // x bf16       [B*T][768]
    uint16_t* bwpre  = W; W += (size_t)DD * DD;
    uint16_t* bwihf  = W; W += (size_t)G4H * DD;
    uint16_t* bwhhf  = W; W += (size_t)G4H * DD;
    uint16_t* bwihr  = W; W += (size_t)G4H * DD;
    uint16_t* bwhhr  = W; W += (size_t)G4H * DD;
    uint16_t* bwproj = W; W += (size_t)DD * 2 * DD;
    uint16_t* preb   = W; W += (size_t)NROWS * DD;     // [T][head][B][64] bf16
    uint16_t* houtb  = W; W += (size_t)NROWS * 2 * DD; // [B][T][1536] bf16

    CvtArgs ca;
    ca.src[0] = x;     ca.dst[0] = xb;     ca.n4[0] = (int)((size_t)NROWS * DD / 4);
    ca.src[1] = pre_w; ca.dst[1] = bwpre;  ca.n4[1] = DD * DD / 4;
    ca.src[2] = wihf;  ca.dst[2] = bwihf;  ca.n4[2] = G4H * DD / 4;
    ca.src[3] = whhf;  ca.dst[3] = bwhhf;  ca.n4[3] = G4H * DD / 4;
    ca.src[4] = wihr;  ca.dst[4] = bwihr;  ca.n4[4] = G4H * DD / 4;
    ca.src[5] = whhr;  ca.dst[5] = bwhhr;  ca.n4[5] = G4H * DD / 4;
    ca.src[6] = projw; ca.dst[6] = bwproj; ca.n4[6] = DD * 2 * DD / 4;
    ca.nseg = 7;
    hipLaunchKernelGGL(cvt_multi, dim3(1024), dim3(256), 0, stream, ca);

    const int RPX = (MT + 7) / 8;            // m-rows per XCD = 25
    const int GBLK = 8 * RPX * NT;           // 1200 blocks (some no-op)

    // S1: pre = x @ pre_w.T + pre_b, bf16, stored [t][head][b][64]
    hipLaunchKernelGGL((gemm128p<1, 1>), dim3(GBLK), dim3(256), 0, stream,
                       xb, bwpre, pre_b, (void*)preb, DD, DD);
    // S2+S3: bidirectional block-diagonal LSTM
    hipLaunchKernelGGL(lstm_fused, dim3(8, 12, 2), dim3(256), 0, stream,
                       preb, bwihf, bwhhf, bwihr, bwhhr,
                       bihf, bhhf, bihr, bhhr, houtb);
    // S4: out = [hf|hr] @ proj_w.T + proj_b, fp32
    hipLaunchKernelGGL((gemm128p<0, 0>), dim3(GBLK), dim3(256), 0, stream,
                       houtb, bwproj, projb, (void*)out, 2 * DD, DD);
}

// Round 5
// 488.730 us; speedup vs baseline: 1.0557x; 1.0142x over previous
//
#include <hip/hip_runtime.h>
#include <stdint.h>

#define DEV __device__ __forceinline__

typedef __attribute__((ext_vector_type(8))) short short8;
typedef __attribute__((ext_vector_type(4))) float floatx4;

// problem dims
#define BATCH 128
#define TT    197
#define DD    768
#define NH    12
#define NROWS (BATCH*TT)   // 25216 = 197*128
#define G4H   3072         // 4*H rows of gate weights
#define MT    197          // m-tiles (128 rows each)
#define NT    6            // n-tiles (128 cols each)

DEV uint16_t f2bf(float f) {
    union { float f; uint32_t u; } v; v.f = f;
    uint32_t r = (v.u + 0x7FFF + ((v.u >> 16) & 1)) >> 16;  // RNE
    return (uint16_t)r;
}

DEV floatx4 mfma16(short8 a, short8 b, floatx4 c) {
    return __builtin_amdgcn_mfma_f32_16x16x32_bf16(a, b, c, 0, 0, 0);
}

DEV float sigf(float x)   { return __builtin_amdgcn_rcpf(1.0f + __expf(-x)); }
DEV float tanhf_(float x) { return 1.0f - 2.0f * __builtin_amdgcn_rcpf(1.0f + __expf(2.0f * x)); }

// async global->LDS, 16B per lane; lds base must be wave-uniform (HW adds lane*16)
DEV void async16(const uint16_t* g, uint16_t* l) {
    __builtin_amdgcn_global_load_lds(
        (const __attribute__((address_space(1))) unsigned int*)g,
        (__attribute__((address_space(3))) unsigned int*)l,
        16, 0, 0);
}

#define CFENCE() asm volatile("" ::: "memory")
// s_waitcnt simm16 encoding (gfx9): vmcnt[3:0]|expcnt[6:4]|lgkmcnt[11:8]|vmcnt[5:4]@[15:14]
#define WAITCNT_LGKM0_ONLY 0xC07F   // lgkmcnt(0), vmcnt/expcnt = no-wait
#define WAITCNT_VM8        0x0F78   // vmcnt(8),   lgkm/expcnt  = no-wait
#define WAITCNT_VM0        0x0F70   // vmcnt(0),   lgkm/expcnt  = no-wait

// ---------------- fused fp32 -> bf16 conversion (all tensors, one launch) ----
struct CvtArgs {
    const float* src[7];
    uint16_t*    dst[7];
    int          n4[7];    // element count / 4
    int          nseg;
};

__global__ void cvt_multi(CvtArgs a) {
    int tid = blockIdx.x * blockDim.x + threadIdx.x;
    int stride = gridDim.x * blockDim.x;
    for (int s = 0; s < a.nseg; s++) {
        const float4* src = (const float4*)a.src[s];
        ushort4* dst = (ushort4*)a.dst[s];
        int n4 = a.n4[s];
        for (int i = tid; i < n4; i += stride) {
            float4 v = src[i];
            ushort4 o;
            o.x = f2bf(v.x); o.y = f2bf(v.y); o.z = f2bf(v.z); o.w = f2bf(v.w);
            dst[i] = o;
        }
    }
}

// ---------------- pipelined bf16 MFMA GEMM: C[M,N] = A[M,K] @ Bw[N,K]^T + bias ----
// 128x128 tile, 4 waves each owning a 64x64 quadrant. BK=32.
// AITER-style software pipeline: 3 LDS buffers, prefetch depth 2, raw s_barrier +
// s_waitcnt vmcnt(8) so the next two iterations' global_load_lds stay IN FLIGHT
// across the barrier. Tail iters clamp into a dump chunk (constant vmcnt math).
// XCD swizzle: bid%8 = XCD; NT same-m blocks consecutive per XCD for L2 A-reuse.
// LAYOUT: 0 = plain [M][Ntot]; 1 = LSTM pre layout [t][head][batch][64].
template<int STORE_BF16, int LAYOUT>
__global__ __launch_bounds__(256) void gemm128p(
    const uint16_t* __restrict__ A,    // [M][K] bf16
    const uint16_t* __restrict__ Bw,   // [N][K] bf16 (weight; transposed use)
    const float*    __restrict__ bias, // [N] fp32
    void*           __restrict__ C,
    int K, int Ntot)
{
    __shared__ __attribute__((aligned(16))) uint16_t As[3][4096];  // 3 x 8 KB
    __shared__ __attribute__((aligned(16))) uint16_t Bs[3][4096];  // 3 x 8 KB
    __shared__ __attribute__((aligned(16))) uint16_t Dump[512];    // 1 KB trash

    // XCD swizzle
    const int bid = blockIdx.x;
    const int c   = bid & 7;
    const int j   = bid >> 3;
    const int mt_ = c + 8 * (j / NT);
    const int nt_ = j % NT;
    if (mt_ >= MT) return;
    const int m0 = mt_ * 128;
    const int n0 = nt_ * 128;

    const int tid  = threadIdx.x;
    const int wv   = tid >> 6;
    const int lane = tid & 63;
    const int ln   = lane & 15;
    const int q    = lane >> 4;
    const int wm   = wv >> 1;   // wave quadrant row
    const int wn   = wv & 1;    // wave quadrant col

    floatx4 acc[4][4];
#pragma unroll
    for (int a = 0; a < 4; a++)
#pragma unroll
        for (int b = 0; b < 4; b++) acc[a][b] = (floatx4){0.f, 0.f, 0.f, 0.f};

    // wave wv stages A chunks {2wv,2wv+1} and B chunks {2wv,2wv+1}
    const uint16_t* gA0 = A  + (size_t)(m0 + (2*wv+0)*16 + ln) * K + q*8;
    const uint16_t* gA1 = A  + (size_t)(m0 + (2*wv+1)*16 + ln) * K + q*8;
    const uint16_t* gB0 = Bw + (size_t)(n0 + (2*wv+0)*16 + ln) * K + q*8;
    const uint16_t* gB1 = Bw + (size_t)(n0 + (2*wv+1)*16 + ln) * K + q*8;

    const int NI = K >> 5;   // 24 (S1) or 48 (S4) — both divisible by 3

    auto stage = [&](int kiter, int buf) {
        int k0 = kiter * 32;
        const bool ok = k0 < K;          // wave-uniform
        if (!ok) k0 = 0;
        uint16_t* a0 = ok ? &As[buf][(2*wv+0)*512] : Dump;
        uint16_t* a1 = ok ? &As[buf][(2*wv+1)*512] : Dump;
        uint16_t* b0 = ok ? &Bs[buf][(2*wv+0)*512] : Dump;
        uint16_t* b1 = ok ? &Bs[buf][(2*wv+1)*512] : Dump;
        async16(gA0 + k0, a0);
        async16(gA1 + k0, a1);
        async16(gB0 + k0, b0);
        async16(gB1 + k0, b1);
    };

    stage(0, 0); stage(1, 1); stage(2, 2);

    for (int i = 0; i < NI; i += 3) {
#pragma unroll
        for (int u = 0; u < 3; u++) {
            CFENCE();
            __builtin_amdgcn_s_waitcnt(WAITCNT_VM8);  // iter i+u's 4 loads landed
            __builtin_amdgcn_s_barrier();              // publish buf u (no full drain)
            CFENCE();

            short8 af[4], bf[4];
#pragma unroll
            for (int mt = 0; mt < 4; mt++)
                af[mt] = *(const short8*)&As[u][(wm*4 + mt)*512 + lane*8];
#pragma unroll
            for (int nt = 0; nt < 4; nt++)
                bf[nt] = *(const short8*)&Bs[u][(wn*4 + nt)*512 + lane*8];
#pragma unroll
            for (int mt = 0; mt < 4; mt++)
#pragma unroll
                for (int nt = 0; nt < 4; nt++)
                    acc[mt][nt] = mfma16(af[mt], bf[nt], acc[mt][nt]);

            CFENCE();
            __builtin_amdgcn_s_barrier();              // all waves done reading buf u
            CFENCE();
            stage(i + u + 3, u);                       // refill (dump-clamped past NI)
        }
    }
    __builtin_amdgcn_s_waitcnt(WAITCNT_VM0);  // drain dump loads before epilogue/exit

    // epilogue: C/D layout col(n)=lane&15, row(m)=(lane>>4)*4+r
#pragma unroll
    for (int mt = 0; mt < 4; mt++)
#pragma unroll
        for (int nt = 0; nt < 4; nt++) {
            int n = n0 + (wn*4 + nt)*16 + ln;
            float bv = bias[n];
#pragma unroll
            for (int r = 0; r < 4; r++) {
                int m = m0 + (wm*4 + mt)*16 + q*4 + r;   // = b*197 + t
                float val = acc[mt][nt][r] + bv;
                if (LAYOUT == 1) {
                    int b = m / 197; int t = m - b*197;
                    int head = n >> 6; int d = n & 63;
                    size_t off = ((size_t)(t*NH + head)*BATCH + b)*64 + d;
                    ((uint16_t*)C)[off] = f2bf(val);
                } else {
                    size_t off = (size_t)m * Ntot + n;
                    if (STORE_BF16) ((uint16_t*)C)[off] = f2bf(val);
                    else            ((float*)C)[off]    = val;
                }
            }
        }
}

// ---------------- fused bidirectional multi-head LSTM ----------------
// grid (8 batch-chunks, 12 heads, 2 dirs), 256 threads = 4 waves (1/SIMD).
// wave w owns units [16w,16w+16): 4 gate-type C-tiles [16 units x 16 batches].
// Persistent weight A-frags in registers; fp32 c-state in registers.
// h exchanged via double-buffered LDS with RAW s_barrier + lgkmcnt(0)-only wait:
// the per-step global h-store and x prefetch stay in flight across the barrier
// (vs __syncthreads' forced vmcnt(0) drain = ~300-500 cyc/step on a 197-step
// serial chain). h stored to global DIRECTLY from C-layout registers.
__global__ __launch_bounds__(256) void lstm_fused(
    const uint16_t* __restrict__ pre,   // [T][head][B][64] bf16
    const uint16_t* __restrict__ wih_f, const uint16_t* __restrict__ whh_f,
    const uint16_t* __restrict__ wih_r, const uint16_t* __restrict__ whh_r,
    const float* __restrict__ bih_f, const float* __restrict__ bhh_f,
    const float* __restrict__ bih_r, const float* __restrict__ bhh_r,
    uint16_t* __restrict__ hout)        // [B][T][1536] bf16
{
    __shared__ __attribute__((aligned(16))) uint16_t hbuf[2][16][72];

    const int tid  = threadIdx.x;
    const int wv   = tid >> 6;
    const int lane = tid & 63;
    const int ln   = lane & 15;
    const int q    = lane >> 4;
    const int b0   = blockIdx.x * 16;
    const int head = blockIdx.y;
    const int dir  = blockIdx.z;
    const int ub   = wv * 16;

    const uint16_t* wih = dir ? wih_r : wih_f;
    const uint16_t* whh = dir ? whh_r : whh_f;
    const float*    bih = dir ? bih_r : bih_f;
    const float*    bhh = dir ? bhh_r : bhh_f;

    // persistent A-fragments: [gate type][k-step]
    short8 aih[4][2], ahh[4][2];
#pragma unroll
    for (int t = 0; t < 4; t++) {
        size_t row = (size_t)(t*768 + head*64 + ub + ln);
#pragma unroll
        for (int s = 0; s < 2; s++) {
            aih[t][s] = *(const short8*)(wih + row*768 + head*64 + s*32 + q*8);
            ahh[t][s] = *(const short8*)(whh + row*768 + head*64 + s*32 + q*8);
        }
    }
    float biasv[4][4];
#pragma unroll
    for (int t = 0; t < 4; t++)
#pragma unroll
        for (int r = 0; r < 4; r++) {
            int row = t*768 + head*64 + ub + q*4 + r;
            biasv[t][r] = bih[row] + bhh[row];
        }

    for (int i = tid; i < 2*16*72; i += 256) ((uint16_t*)hbuf)[i] = 0;
    float c[4] = {0.f, 0.f, 0.f, 0.f};
    __syncthreads();

    // x: [t][head][b][64]; wave reads 2 KB contiguous per step
    const uint16_t* xbase = pre + (size_t)head*BATCH*64 + (size_t)(b0 + ln)*64 + q*8;
    // direct h-store base: lane (ln,q) of wave wv owns units ub+q*4..+3, batch b0+ln
    uint16_t* hw = hout + ((size_t)(b0 + ln)*TT)*1536 + dir*768 + head*64 + ub + q*4;

    int t_cur = dir ? (TT - 1) : 0;
    const int tstep = dir ? -1 : 1;
    size_t xo = (size_t)t_cur * NH * BATCH * 64;
    short8 xv0 = *(const short8*)(xbase + xo);
    short8 xv1 = *(const short8*)(xbase + xo + 32);

    for (int step = 0; step < TT; step++) {
        short8 cx0 = xv0, cx1 = xv1;
        int t_next = t_cur + tstep;
        if (step + 1 < TT) {   // prefetch next timestep's x (coalesced)
            size_t xo2 = (size_t)t_next * NH * BATCH * 64;
            xv0 = *(const short8*)(xbase + xo2);
            xv1 = *(const short8*)(xbase + xo2 + 32);
        }
        const int pb = (step + 1) & 1;   // buffer holding h_{step-1}
        const int cb = step & 1;         // buffer to write h_step
        short8 hb0 = *(const short8*)&hbuf[pb][ln][0*32 + q*8];
        short8 hb1 = *(const short8*)&hbuf[pb][ln][1*32 + q*8];

        floatx4 acc[4];
#pragma unroll
        for (int t = 0; t < 4; t++)
            acc[t] = (floatx4){biasv[t][0], biasv[t][1], biasv[t][2], biasv[t][3]};
#pragma unroll
        for (int t = 0; t < 4; t++) {
            acc[t] = mfma16(aih[t][0], cx0, acc[t]);   // x part first: independent of hb
            acc[t] = mfma16(ahh[t][0], hb0, acc[t]);
            acc[t] = mfma16(aih[t][1], cx1, acc[t]);
            acc[t] = mfma16(ahh[t][1], hb1, acc[t]);
        }

        union { uint16_t s[4]; uint2 v; } hp;
#pragma unroll
        for (int r = 0; r < 4; r++) {
            float ig = sigf(acc[0][r]);
            float fg = sigf(acc[1][r]);
            float gg = tanhf_(acc[2][r]);
            float og = sigf(acc[3][r]);
            c[r] = fg * c[r] + ig * gg;
            float hv = og * tanhf_(c[r]);
            hp.s[r] = f2bf(hv);
        }

        // exchange write into the OTHER buffer (no conflict with laggard readers)
        *(uint2*)&hbuf[cb][ln][ub + q*4] = hp.v;
        // direct global store from C-layout regs: fire-and-forget, NOT drained below
        *(uint2*)(hw + (size_t)t_cur * 1536) = hp.v;

        CFENCE();
        __builtin_amdgcn_s_waitcnt(WAITCNT_LGKM0_ONLY);  // LDS write visible...
        __builtin_amdgcn_s_barrier();                     // ...to all waves
        CFENCE();

        t_cur = t_next;
    }
}

extern "C" void kernel_launch(void* const* d_in, const int* in_sizes, int n_in,
                              void* d_out, int out_size, void* d_ws, size_t ws_size,
                              hipStream_t stream) {
    (void)in_sizes; (void)n_in; (void)out_size; (void)ws_size;
    const float* x     = (const float*)d_in[0];
    const float* pre_w = (const float*)d_in[1];
    const float* pre_b = (const float*)d_in[2];
    const float* wihf  = (const float*)d_in[3];
    const float* whhf  = (const float*)d_in[4];
    const float* bihf  = (const float*)d_in[5];
    const float* bhhf  = (const float*)d_in[6];
    const float* wihr  = (const float*)d_in[7];
    const float* whhr  = (const float*)d_in[8];
    const float* bihr  = (const float*)d_in[9];
    const float* bhhr  = (const float*)d_in[10];
    const float* projw = (const float*)d_in[11];
    const float* projb = (const float*)d_in[12];
    float* out = (float*)d_out;

    // workspace layout (bf16 elements), ~177 MB total
    uint16_t* W = (uint16_t*)d_ws;
    uint16_t* xb     = W; W += (size_t)NROWS * DD;     // x bf16       [B*T][768]
    uint16_t* bwpre  = W; W += (size_t)DD * DD;
    uint16_t* bwihf  = W; W += (size_t)G4H * DD;
    uint16_t* bwhhf  = W; W += (size_t)G4H * DD;
    uint16_t* bwihr  = W; W += (size_t)G4H * DD;
    uint16_t* bwhhr  = W; W += (size_t)G4H * DD;
    uint16_t* bwproj = W; W += (size_t)DD * 2 * DD;
    uint16_t* preb   = W; W += (size_t)NROWS * DD;     // [T][head][B][64] bf16
    uint16_t* houtb  = W; W += (size_t)NROWS * 2 * DD; // [B][T][1536] bf16

    CvtArgs ca;
    ca.src[0] = x;     ca.dst[0] = xb;     ca.n4[0] = (int)((size_t)NROWS * DD / 4);
    ca.src[1] = pre_w; ca.dst[1] = bwpre;  ca.n4[1] = DD * DD / 4;
    ca.src[2] = wihf;  ca.dst[2] = bwihf;  ca.n4[2] = G4H * DD / 4;
    ca.src[3] = whhf;  ca.dst[3] = bwhhf;  ca.n4[3] = G4H * DD / 4;
    ca.src[4] = wihr;  ca.dst[4] = bwihr;  ca.n4[4] = G4H * DD / 4;
    ca.src[5] = whhr;  ca.dst[5] = bwhhr;  ca.n4[5] = G4H * DD / 4;
    ca.src[6] = projw; ca.dst[6] = bwproj; ca.n4[6] = DD * 2 * DD / 4;
    ca.nseg = 7;
    hipLaunchKernelGGL(cvt_multi, dim3(1024), dim3(256), 0, stream, ca);

    const int RPX = (MT + 7) / 8;            // m-rows per XCD = 25
    const int GBLK = 8 * RPX * NT;           // 1200 blocks (some no-op)

    // S1: pre = x @ pre_w.T + pre_b, bf16, stored [t][head][b][64]
    hipLaunchKernelGGL((gemm128p<1, 1>), dim3(GBLK), dim3(256), 0, stream,
                       xb, bwpre, pre_b, (void*)preb, DD, DD);
    // S2+S3: bidirectional block-diagonal LSTM
    hipLaunchKernelGGL(lstm_fused, dim3(8, 12, 2), dim3(256), 0, stream,
                       preb, bwihf, bwhhf, bwihr, bwhhr,
                       bihf, bhhf, bihr, bhhr, houtb);
    // S4: out = [hf|hr] @ proj_w.T + proj_b, fp32
    hipLaunchKernelGGL((gemm128p<0, 0>), dim3(GBLK), dim3(256), 0, stream,
                       houtb, bwproj, projb, (void*)out, 2 * DD, DD);
}